// Round 7
// baseline (5459.047 us; speedup 1.0000x reference)
//
#include <hip/hip_runtime.h>
#include <stdint.h>

// Problem constants (fixed by setup_inputs): B=8, L=K=2048, D=64
#define BATCH 8
#define NPTS  2048
#define DIM   64
#define VECN  (BATCH*NPTS)   // 16384
#define KH    1024           // split-K half width
#define CHUNK 64             // columns staged per LDS buffer
#define NCHUNK (KH/CHUNK)    // 16

typedef __attribute__((ext_vector_type(8))) short bf16x8;
typedef __attribute__((ext_vector_type(4))) float f32x4;

#define IL2 1.4426950408889634f
#define LN2 0.6931471805599453f
#define SCV 1.6986436f       // sqrt(2*log2(e)): inputs pre-scaled so MFMA dot is in log2 units

__device__ inline float fexp2(float x) { return __builtin_amdgcn_exp2f(x); }
__device__ inline float flog2(float x) { return __builtin_amdgcn_logf(x); }

// async global->LDS staging (lds dest = uniform base + lane*size; global src per-lane)
__device__ inline void gload_lds16(const void* g, void* l) {
  __builtin_amdgcn_global_load_lds(
      (const __attribute__((address_space(1))) uint32_t*)g,
      (__attribute__((address_space(3))) uint32_t*)l, 16, 0, 0);
}
__device__ inline void gload_lds4(const void* g, void* l) {
  __builtin_amdgcn_global_load_lds(
      (const __attribute__((address_space(1))) uint32_t*)g,
      (__attribute__((address_space(3))) uint32_t*)l, 4, 0, 0);
}

// ---- workspace layout (bytes) ----
static constexpr size_t XB_OFF   = 0;                                   // bf16 scaled x : 2 MB
static constexpr size_t YB_OFF   = (size_t)VECN * DIM * 2;              // bf16 scaled y : 2 MB
static constexpr size_t NHX_OFF  = YB_OFF * 2;                          // 0.5*||bf(x*SCV)||^2
static constexpr size_t NHY_OFF  = NHX_OFF + (size_t)VECN * 4;
static constexpr size_t LA2_OFF  = NHY_OFF + (size_t)VECN * 4;          // log2(a)
static constexpr size_t LB2_OFF  = LA2_OFF + (size_t)VECN * 4;          // log2(b)
static constexpr size_t POT_OFF  = LB2_OFF + (size_t)VECN * 4;          // 4 pots
static constexpr size_t CW_OFF   = POT_OFF + (size_t)4 * VECN * 4;      // per-job col coeff w - nh_v
static constexpr size_t PM_OFF   = CW_OFF + (size_t)4 * VECN * 4;       // partial max/R [2][4][VECN]
static constexpr size_t PS_OFF   = PM_OFF + (size_t)8 * VECN * 4;       // partial sum [2][4][VECN]
static constexpr size_t FOUT_OFF = PS_OFF + (size_t)8 * VECN * 4;       // f,g,ge,fe
static constexpr size_t R_OFF    = FOUT_OFF + (size_t)4 * VECN * 4;     // per-row lse (log2) [4][VECN]

__device__ inline ushort f2bf(float f) {
  uint32_t u = __float_as_uint(f);
  u += 0x7fffu + ((u >> 16) & 1u);   // RNE
  return (ushort)(u >> 16);
}

// One wave per row: scale by SCV, convert to bf16; norm from the ROUNDED values
// (nh = 0.5*sum(bf(v*SCV)^2) = log2e*||v_eff||^2, exactly consistent with the MFMA dot).
__global__ void prep_convert(const float* __restrict__ x, const float* __restrict__ y,
                             ushort* __restrict__ xb, ushort* __restrict__ yb,
                             float* __restrict__ nhx, float* __restrict__ nhy) {
  int wid  = (blockIdx.x * blockDim.x + threadIdx.x) >> 6;
  int lane = threadIdx.x & 63;
  const float* src; ushort* dst; float* nrm; int row;
  if (wid < VECN) { src = x; dst = xb; nrm = nhx; row = wid; }
  else            { src = y; dst = yb; nrm = nhy; row = wid - VECN; }
  float v = src[(size_t)row * DIM + lane] * SCV;
  ushort us = f2bf(v);
  dst[(size_t)row * DIM + lane] = us;
  float vb = __uint_as_float(((uint32_t)us) << 16);
  float sq = vb * vb;
  #pragma unroll
  for (int off = 32; off; off >>= 1) sq += __shfl_xor(sq, off);
  if (lane == 0) nrm[row] = 0.5f * sq;
}

// log2-weights, zero pots, init cw[z] = lw_col - nh_col (pot=0).
__global__ void prep_vecs(const float* __restrict__ a, const float* __restrict__ b,
                          const float* __restrict__ nhx, const float* __restrict__ nhy,
                          float* __restrict__ la2, float* __restrict__ lb2,
                          float* __restrict__ pot, float* __restrict__ cw) {
  int i = blockIdx.x * blockDim.x + threadIdx.x;
  float l2a = log2f(a[i]);
  float l2b = log2f(b[i]);
  la2[i] = l2a;
  lb2[i] = l2b;
  float hx = nhx[i], hy = nhy[i];
  cw[i]                    = l2a - hx;   // z0 xx: cols x, weight a
  cw[(size_t)VECN + i]     = l2b - hy;   // z1 yy: cols y, weight b
  cw[(size_t)2 * VECN + i] = l2b - hy;   // z2 xy: cols y, weight b (pot pyx)
  cw[(size_t)3 * VECN + i] = l2a - hx;   // z3 yx: cols x, weight a (pot pxy)
  #pragma unroll
  for (int j = 0; j < 4; ++j) pot[(size_t)j * VECN + i] = 0.f;
}

// Fused flash-LSE partial kernel: LDS-staged V (XOR-swizzled), bias in MFMA C-operand.
// MODE 0: per-thread online max (safe; iteration 0).
// MODE 1: fixed per-row normalizer R from previous iteration's lse (1 exp2/entry).
// grid: ((NPTS/64)*2, BATCH, 4 jobs); block 256 (4 waves, 16 rows each)
template<int MODE>
__global__ __launch_bounds__(256, 8)
void extrap_kernel(const ushort* __restrict__ xb, const ushort* __restrict__ yb,
                   const float* __restrict__ nhx, const float* __restrict__ nhy,
                   const float* __restrict__ cwarr, const float* __restrict__ Rarr,
                   float* __restrict__ pm, float* __restrict__ ps) {
  __shared__ char  vlds[2][CHUNK * 128];   // 2 x 8 KB, swizzled V rows
  __shared__ float cwlds[2][CHUNK];        // 2 x 256 B, per-col bias

  const int rb    = blockIdx.x >> 1;
  const int half  = blockIdx.x & 1;
  const int batch = blockIdx.y;
  const int z     = blockIdx.z;
  const ushort *U, *V; const float *nU;
  switch (z) {
    case 0:  U = xb; V = xb; nU = nhx; break; // xx
    case 1:  U = yb; V = yb; nU = nhy; break; // yy
    case 2:  U = xb; V = yb; nU = nhx; break; // xy (rows x, cols y)
    default: U = yb; V = xb; nU = nhy; break; // yx (rows y, cols x)
  }
  const int lane = threadIdx.x & 63;
  const int w    = threadIdx.x >> 6;
  const int g    = lane >> 4;
  const int c    = lane & 15;
  const int rowbase = rb * 64 + w * 16;

  const ushort* Ub   = U + ((size_t)batch * NPTS + rowbase) * DIM;
  const char*   Vch  = (const char*)(V + ((size_t)batch * NPTS + half * KH) * DIM); // 128B rows
  const char*   cwch = (const char*)(cwarr + (size_t)z * VECN + (size_t)batch * NPTS + half * KH);

  // A fragments: lane holds U[row=c][k = g*8 .. +8) (and +32 for second mfma)
  bf16x8 a0 = *(const bf16x8*)(Ub + (size_t)c * DIM + g * 8);
  bf16x8 a1 = *(const bf16x8*)(Ub + (size_t)c * DIM + 32 + g * 8);

  float q[4];    // per accumulator row: -(nh_row [+ R_row])
  float Rr[4];   // MODE 1: fixed normalizer per row
  #pragma unroll
  for (int r = 0; r < 4; ++r) {
    size_t rowi = (size_t)batch * NPTS + rowbase + g * 4 + r;
    if (MODE == 1) {
      Rr[r] = Rarr[(size_t)z * VECN + rowi];
      q[r] = -(nU[rowi] + Rr[r]);
    } else {
      q[r] = -nU[rowi];
    }
  }

  // pre-swizzled staging offset: row rr=lane>>3, byte o=(lane&7)*16; source fetches
  // V[rr][o ^ ((rr&7)<<4)] so the swizzled read returns V[rr][qq] at qq^xr.
  const size_t lane_voff = ((size_t)(lane >> 3)) * 128
                         + (size_t)((((lane & 7) ^ (lane >> 3)) << 4));

  float s[4] = {0.f, 0.f, 0.f, 0.f};
  float m[4];
  #pragma unroll
  for (int r = 0; r < 4; ++r) m[r] = -INFINITY;

  auto stage = [&](int p, int ck) {
    const char* gbase = Vch + (size_t)ck * CHUNK * 128;
    #pragma unroll
    for (int i = 0; i < 2; ++i) {
      int j = w * 2 + i;                                  // 1 KB slab = 8 rows
      gload_lds16(gbase + (size_t)j * 1024 + lane_voff, &vlds[p][j * 1024]);
    }
    if (w == 0) gload_lds4(cwch + (size_t)ck * CHUNK * 4 + lane * 4, &cwlds[p][0]);
  };

  auto compute = [&](int p) {
    #pragma unroll
    for (int t = 0; t < 2; ++t) {
      const int rr0 = t * 32 + c;
      const int rr1 = rr0 + 16;
      const int x0 = (rr0 & 7) << 4;           // rr1&7 == rr0&7
      const char* pv0 = &vlds[p][rr0 * 128];
      const char* pv1 = &vlds[p][rr1 * 128];
      bf16x8 b0a = *(const bf16x8*)(pv0 + ((g * 16) ^ x0));
      bf16x8 b0b = *(const bf16x8*)(pv0 + ((64 + g * 16) ^ x0));
      bf16x8 b1a = *(const bf16x8*)(pv1 + ((g * 16) ^ x0));
      bf16x8 b1b = *(const bf16x8*)(pv1 + ((64 + g * 16) ^ x0));
      float cw0 = cwlds[p][rr0];
      float cw1 = cwlds[p][rr1];

      f32x4 acc0 = {cw0, cw0, cw0, cw0};       // bias folded into MFMA C-operand
      f32x4 acc1 = {cw1, cw1, cw1, cw1};
      acc0 = __builtin_amdgcn_mfma_f32_16x16x32_bf16(a0, b0a, acc0, 0, 0, 0);
      acc0 = __builtin_amdgcn_mfma_f32_16x16x32_bf16(a1, b0b, acc0, 0, 0, 0);
      acc1 = __builtin_amdgcn_mfma_f32_16x16x32_bf16(a0, b1a, acc1, 0, 0, 0);
      acc1 = __builtin_amdgcn_mfma_f32_16x16x32_bf16(a1, b1b, acc1, 0, 0, 0);

      #pragma unroll
      for (int r = 0; r < 4; ++r) {
        if (MODE == 1) {
          float e0 = fexp2(acc0[r] + q[r]);
          float e1 = fexp2(acc1[r] + q[r]);
          s[r] += e0 + e1;
        } else {
          float t0 = acc0[r] + q[r];
          float t1 = acc1[r] + q[r];
          float mn = fmaxf(m[r], fmaxf(t0, t1));     // v_max3
          s[r] = fmaf(s[r], fexp2(m[r] - mn), fexp2(t0 - mn) + fexp2(t1 - mn));
          m[r] = mn;
        }
      }
    }
  };

  stage(0, 0);
  __syncthreads();
  int p = 0;
  for (int ck = 0; ck < NCHUNK; ++ck) {
    if (ck < NCHUNK - 1) stage(p ^ 1, ck + 1);   // prefetch in flight during compute
    compute(p);
    __syncthreads();                             // drains vmcnt+lgkmcnt for the staged buffer
    p ^= 1;
  }

  if (MODE == 1) {
    // pure add-reduce across the 16 lanes of each group (disjoint column subsets)
    #pragma unroll
    for (int r = 0; r < 4; ++r) {
      #pragma unroll
      for (int off = 1; off < 16; off <<= 1) s[r] += __shfl_xor(s[r], off);
    }
  } else {
    // online merge across 16 lanes
    #pragma unroll
    for (int r = 0; r < 4; ++r) {
      #pragma unroll
      for (int off = 1; off < 16; off <<= 1) {
        float mo = __shfl_xor(m[r], off);
        float so = __shfl_xor(s[r], off);
        float mn = fmaxf(m[r], mo);
        s[r] = fmaf(s[r], fexp2(m[r] - mn), so * fexp2(mo - mn));
        m[r] = mn;
      }
    }
  }
  if (c == 0) {
    #pragma unroll
    for (int r = 0; r < 4; ++r) {
      size_t idx = (size_t)(half * 4 + z) * VECN + (size_t)batch * NPTS + rowbase + g * 4 + r;
      pm[idx] = (MODE == 1) ? Rr[r] : m[r];
      ps[idx] = s[r];
    }
  }
}

// Combine split-K partials, 0.5-averaging, rebuild consumer cw; store per-row lse (R).
__global__ void merge_kernel(const float* __restrict__ pm, const float* __restrict__ ps,
                             float* __restrict__ pot,
                             const float* __restrict__ la2, const float* __restrict__ lb2,
                             const float* __restrict__ nhx, const float* __restrict__ nhy,
                             float* __restrict__ cw, float* __restrict__ Rarr,
                             float* __restrict__ fouts, int avg) {
  int i = blockIdx.x * blockDim.x + threadIdx.x;       // 0 .. 4*VECN
  int z = i >> 14;                                     // VECN = 16384
  int iin = i & (VECN - 1);
  float m0 = pm[i], m1 = pm[(size_t)4 * VECN + i];
  float s0 = ps[i], s1 = ps[(size_t)4 * VECN + i];
  float mn = fmaxf(m0, m1);
  float s  = fmaf(s0, fexp2(m0 - mn), s1 * fexp2(m1 - mn));
  s = fmaxf(s, 1e-38f);                                // guard log2(0)
  float lse = mn + flog2(s);                           // log2-units row LSE
  float val = -LN2 * lse;
  if (avg) {
    val = 0.5f * (val + pot[i]);
    pot[i] = val;
    Rarr[i] = lse;                                     // normalizer for this job's next pass
    int cjob = z ^ (z >> 1);                           // 0,1 self; 2<->3
    bool colx = (cjob == 0 || cjob == 3);              // consumer's column side
    const float* lw2 = colx ? la2 : lb2;
    const float* nh  = colx ? nhx : nhy;
    float wv = fmaf(val, IL2, lw2[iin]);
    cw[(size_t)cjob * VECN + iin] = wv - nh[iin];
  } else {
    fouts[i] = val;
  }
}

// res = ( sum (ge-f)*a + sum (fe-g)*b ) / BATCH  -> single scalar
__global__ void reduce_kernel(const float* __restrict__ fouts,
                              const float* __restrict__ a, const float* __restrict__ b,
                              float* __restrict__ out) {
  const float* f  = fouts;
  const float* g  = fouts + (size_t)VECN;
  const float* ge = fouts + (size_t)2 * VECN;
  const float* fe = fouts + (size_t)3 * VECN;
  int tid = threadIdx.x;
  float acc = 0.f;
  for (int i = tid; i < VECN; i += 1024)
    acc += (ge[i] - f[i]) * a[i] + (fe[i] - g[i]) * b[i];
  #pragma unroll
  for (int off = 32; off; off >>= 1) acc += __shfl_xor(acc, off);
  __shared__ float red[16];
  if ((tid & 63) == 0) red[tid >> 6] = acc;
  __syncthreads();
  if (tid < 64) {
    float v = (tid < 16) ? red[tid] : 0.f;
    #pragma unroll
    for (int off = 8; off; off >>= 1) v += __shfl_xor(v, off);
    if (tid == 0) out[0] = v / (float)BATCH;
  }
}

extern "C" void kernel_launch(void* const* d_in, const int* in_sizes, int n_in,
                              void* d_out, int out_size, void* d_ws, size_t ws_size,
                              hipStream_t stream) {
  const float* x = (const float*)d_in[0];
  const float* a = (const float*)d_in[1];
  const float* y = (const float*)d_in[2];
  const float* b = (const float*)d_in[3];
  char* ws = (char*)d_ws;
  ushort* xb  = (ushort*)(ws + XB_OFF);
  ushort* yb  = (ushort*)(ws + YB_OFF);
  float* nhx  = (float*)(ws + NHX_OFF);
  float* nhy  = (float*)(ws + NHY_OFF);
  float* la2  = (float*)(ws + LA2_OFF);
  float* lb2  = (float*)(ws + LB2_OFF);
  float* pot  = (float*)(ws + POT_OFF);
  float* cw   = (float*)(ws + CW_OFF);
  float* pm   = (float*)(ws + PM_OFF);
  float* ps   = (float*)(ws + PS_OFF);
  float* fouts= (float*)(ws + FOUT_OFF);
  float* Rarr = (float*)(ws + R_OFF);

  prep_convert<<<dim3(2 * VECN / 4), 256, 0, stream>>>(x, y, xb, yb, nhx, nhy);
  prep_vecs<<<dim3(VECN / 256), 256, 0, stream>>>(a, b, nhx, nhy, la2, lb2, pot, cw);

  const dim3 eg((NPTS / 64) * 2, BATCH, 4);
  // iteration 0: online-max (safe, seeds R)
  extrap_kernel<0><<<eg, 256, 0, stream>>>(xb, yb, nhx, nhy, cw, Rarr, pm, ps);
  merge_kernel<<<dim3(4 * VECN / 256), 256, 0, stream>>>(
      pm, ps, pot, la2, lb2, nhx, nhy, cw, Rarr, fouts, 1);
  // iterations 1..9: fixed-R fast path
  for (int it = 1; it < 10; ++it) {
    extrap_kernel<1><<<eg, 256, 0, stream>>>(xb, yb, nhx, nhy, cw, Rarr, pm, ps);
    merge_kernel<<<dim3(4 * VECN / 256), 256, 0, stream>>>(
        pm, ps, pot, la2, lb2, nhx, nhy, cw, Rarr, fouts, 1);
  }
  // final extrapolation (no averaging) -> f, g, ge, fe
  extrap_kernel<1><<<eg, 256, 0, stream>>>(xb, yb, nhx, nhy, cw, Rarr, pm, ps);
  merge_kernel<<<dim3(4 * VECN / 256), 256, 0, stream>>>(
      pm, ps, pot, la2, lb2, nhx, nhy, cw, Rarr, fouts, 0);

  reduce_kernel<<<1, 1024, 0, stream>>>(fouts, a, b, (float*)d_out);
}

// Round 8
// 5181.140 us; speedup vs baseline: 1.0536x; 1.0536x over previous
//
#include <hip/hip_runtime.h>
#include <stdint.h>

// Problem constants (fixed by setup_inputs): B=8, L=K=2048, D=64
#define BATCH 8
#define NPTS  2048
#define DIM   64
#define VECN  (BATCH*NPTS)   // 16384
#define KH    1024           // split-K half width
#define CHUNK 64             // columns staged per LDS buffer
#define NCHUNK (KH/CHUNK)    // 16

typedef __attribute__((ext_vector_type(8))) short bf16x8;
typedef __attribute__((ext_vector_type(4))) float f32x4;

#define IL2 1.4426950408889634f
#define LN2 0.6931471805599453f
#define SCV 1.6986436f       // sqrt(2*log2(e)): inputs pre-scaled so MFMA dot is in log2 units

__device__ inline float fexp2(float x) { return __builtin_amdgcn_exp2f(x); }
__device__ inline float flog2(float x) { return __builtin_amdgcn_logf(x); }

// async global->LDS staging (lds dest = uniform base + lane*size; global src per-lane)
__device__ inline void gload_lds16(const void* g, void* l) {
  __builtin_amdgcn_global_load_lds(
      (const __attribute__((address_space(1))) uint32_t*)g,
      (__attribute__((address_space(3))) uint32_t*)l, 16, 0, 0);
}
__device__ inline void gload_lds4(const void* g, void* l) {
  __builtin_amdgcn_global_load_lds(
      (const __attribute__((address_space(1))) uint32_t*)g,
      (__attribute__((address_space(3))) uint32_t*)l, 4, 0, 0);
}

// ---- workspace layout (bytes) ----
static constexpr size_t XB_OFF   = 0;                                   // bf16 scaled x : 2 MB
static constexpr size_t YB_OFF   = (size_t)VECN * DIM * 2;              // bf16 scaled y : 2 MB
static constexpr size_t NHX_OFF  = YB_OFF * 2;                          // 0.5*||bf(x*SCV)||^2
static constexpr size_t NHY_OFF  = NHX_OFF + (size_t)VECN * 4;
static constexpr size_t LA2_OFF  = NHY_OFF + (size_t)VECN * 4;          // log2(a)
static constexpr size_t LB2_OFF  = LA2_OFF + (size_t)VECN * 4;          // log2(b)
static constexpr size_t POT_OFF  = LB2_OFF + (size_t)VECN * 4;          // 4 pots
static constexpr size_t CW_OFF   = POT_OFF + (size_t)4 * VECN * 4;      // per-job col coeff w - nh_v
static constexpr size_t PM_OFF   = CW_OFF + (size_t)4 * VECN * 4;       // partial max/R [2][4][VECN]
static constexpr size_t PS_OFF   = PM_OFF + (size_t)8 * VECN * 4;       // partial sum [2][4][VECN]
static constexpr size_t FOUT_OFF = PS_OFF + (size_t)8 * VECN * 4;       // f,g,ge,fe
static constexpr size_t R_OFF    = FOUT_OFF + (size_t)4 * VECN * 4;     // per-row lse (log2) [4][VECN]

__device__ inline ushort f2bf(float f) {
  uint32_t u = __float_as_uint(f);
  u += 0x7fffu + ((u >> 16) & 1u);   // RNE
  return (ushort)(u >> 16);
}

// One wave per row: scale by SCV, convert to bf16; norm from the ROUNDED values
// (nh = 0.5*sum(bf(v*SCV)^2) = log2e*||v_eff||^2, exactly consistent with the MFMA dot).
__global__ void prep_convert(const float* __restrict__ x, const float* __restrict__ y,
                             ushort* __restrict__ xb, ushort* __restrict__ yb,
                             float* __restrict__ nhx, float* __restrict__ nhy) {
  int wid  = (blockIdx.x * blockDim.x + threadIdx.x) >> 6;
  int lane = threadIdx.x & 63;
  const float* src; ushort* dst; float* nrm; int row;
  if (wid < VECN) { src = x; dst = xb; nrm = nhx; row = wid; }
  else            { src = y; dst = yb; nrm = nhy; row = wid - VECN; }
  float v = src[(size_t)row * DIM + lane] * SCV;
  ushort us = f2bf(v);
  dst[(size_t)row * DIM + lane] = us;
  float vb = __uint_as_float(((uint32_t)us) << 16);
  float sq = vb * vb;
  #pragma unroll
  for (int off = 32; off; off >>= 1) sq += __shfl_xor(sq, off);
  if (lane == 0) nrm[row] = 0.5f * sq;
}

// log2-weights, zero pots, init cw[z] = lw_col - nh_col (pot=0).
__global__ void prep_vecs(const float* __restrict__ a, const float* __restrict__ b,
                          const float* __restrict__ nhx, const float* __restrict__ nhy,
                          float* __restrict__ la2, float* __restrict__ lb2,
                          float* __restrict__ pot, float* __restrict__ cw) {
  int i = blockIdx.x * blockDim.x + threadIdx.x;
  float l2a = log2f(a[i]);
  float l2b = log2f(b[i]);
  la2[i] = l2a;
  lb2[i] = l2b;
  float hx = nhx[i], hy = nhy[i];
  cw[i]                    = l2a - hx;   // z0 xx: cols x, weight a
  cw[(size_t)VECN + i]     = l2b - hy;   // z1 yy: cols y, weight b
  cw[(size_t)2 * VECN + i] = l2b - hy;   // z2 xy: cols y, weight b (pot pyx)
  cw[(size_t)3 * VECN + i] = l2a - hx;   // z3 yx: cols x, weight a (pot pxy)
  #pragma unroll
  for (int j = 0; j < 4; ++j) pot[(size_t)j * VECN + i] = 0.f;
}

// ---- shared pieces of the two extrap kernels (macro to keep codegen identical) ----
#define EXTRAP_PROLOGUE                                                                \
  __shared__ char  vlds[2][CHUNK * 128];                                               \
  __shared__ float cwlds[2][CHUNK];                                                    \
  const int rb    = blockIdx.x >> 1;                                                   \
  const int half  = blockIdx.x & 1;                                                    \
  const int batch = blockIdx.y;                                                        \
  const int z     = blockIdx.z;                                                        \
  const ushort *U, *V; const float *nU;                                                \
  switch (z) {                                                                         \
    case 0:  U = xb; V = xb; nU = nhx; break;                                          \
    case 1:  U = yb; V = yb; nU = nhy; break;                                          \
    case 2:  U = xb; V = yb; nU = nhx; break;                                          \
    default: U = yb; V = xb; nU = nhy; break;                                          \
  }                                                                                    \
  const int lane = threadIdx.x & 63;                                                   \
  const int w    = threadIdx.x >> 6;                                                   \
  const int g    = lane >> 4;                                                          \
  const int c    = lane & 15;                                                          \
  const int rowbase = rb * 64 + w * 16;                                                \
  const ushort* Ub   = U + ((size_t)batch * NPTS + rowbase) * DIM;                     \
  const char*   Vch  = (const char*)(V + ((size_t)batch * NPTS + half * KH) * DIM);    \
  const char*   cwch = (const char*)(cwarr + (size_t)z * VECN +                        \
                                     (size_t)batch * NPTS + half * KH);                \
  bf16x8 a0 = *(const bf16x8*)(Ub + (size_t)c * DIM + g * 8);                          \
  bf16x8 a1 = *(const bf16x8*)(Ub + (size_t)c * DIM + 32 + g * 8);                     \
  const size_t lane_voff = ((size_t)(lane >> 3)) * 128                                 \
                         + (size_t)((((lane & 7) ^ (lane >> 3)) << 4));

#define EXTRAP_STAGE(p, ck) {                                                          \
  const char* gbase = Vch + (size_t)(ck) * CHUNK * 128;                                \
  _Pragma("unroll")                                                                    \
  for (int i_ = 0; i_ < 2; ++i_) {                                                     \
    int j_ = w * 2 + i_;                                                               \
    gload_lds16(gbase + (size_t)j_ * 1024 + lane_voff, &vlds[p][j_ * 1024]);           \
  }                                                                                    \
  if (w == 0) gload_lds4(cwch + (size_t)(ck) * CHUNK * 4 + lane * 4, &cwlds[p][0]);    \
}

#define EXTRAP_MFMA(p, t, acc0, acc1, cw0, cw1)                                        \
  const int rr0 = (t) * 32 + c;                                                        \
  const int rr1 = rr0 + 16;                                                            \
  const int x0 = (rr0 & 7) << 4;                                                       \
  const char* pv0 = &vlds[p][rr0 * 128];                                               \
  const char* pv1 = &vlds[p][rr1 * 128];                                               \
  bf16x8 b0a = *(const bf16x8*)(pv0 + ((g * 16) ^ x0));                                \
  bf16x8 b0b = *(const bf16x8*)(pv0 + ((64 + g * 16) ^ x0));                           \
  bf16x8 b1a = *(const bf16x8*)(pv1 + ((g * 16) ^ x0));                                \
  bf16x8 b1b = *(const bf16x8*)(pv1 + ((64 + g * 16) ^ x0));                           \
  float cw0 = cwlds[p][rr0];                                                           \
  float cw1 = cwlds[p][rr1];                                                           \
  f32x4 acc0 = {cw0, cw0, cw0, cw0};                                                   \
  f32x4 acc1 = {cw1, cw1, cw1, cw1};                                                   \
  acc0 = __builtin_amdgcn_mfma_f32_16x16x32_bf16(a0, b0a, acc0, 0, 0, 0);              \
  acc0 = __builtin_amdgcn_mfma_f32_16x16x32_bf16(a1, b0b, acc0, 0, 0, 0);              \
  acc1 = __builtin_amdgcn_mfma_f32_16x16x32_bf16(a0, b1a, acc1, 0, 0, 0);              \
  acc1 = __builtin_amdgcn_mfma_f32_16x16x32_bf16(a1, b1b, acc1, 0, 0, 0);

// Iteration-0 kernel: per-thread online max (safe), seeds R.
__global__ __launch_bounds__(256, 8)
void extrap_online(const ushort* __restrict__ xb, const ushort* __restrict__ yb,
                   const float* __restrict__ nhx, const float* __restrict__ nhy,
                   const float* __restrict__ cwarr,
                   float* __restrict__ pm, float* __restrict__ ps) {
  EXTRAP_PROLOGUE
  float q[4];
  #pragma unroll
  for (int r = 0; r < 4; ++r)
    q[r] = -nU[(size_t)batch * NPTS + rowbase + g * 4 + r];

  float s[4] = {0.f, 0.f, 0.f, 0.f};
  float m[4];
  #pragma unroll
  for (int r = 0; r < 4; ++r) m[r] = -INFINITY;

  EXTRAP_STAGE(0, 0)
  __syncthreads();
  int p = 0;
  for (int ck = 0; ck < NCHUNK; ++ck) {
    if (ck < NCHUNK - 1) EXTRAP_STAGE(p ^ 1, ck + 1)
    #pragma unroll
    for (int t = 0; t < 2; ++t) {
      EXTRAP_MFMA(p, t, acc0, acc1, cw0, cw1)
      #pragma unroll
      for (int r = 0; r < 4; ++r) {
        float t0 = acc0[r] + q[r];
        float t1 = acc1[r] + q[r];
        float mn = fmaxf(m[r], fmaxf(t0, t1));     // v_max3
        s[r] = fmaf(s[r], fexp2(m[r] - mn), fexp2(t0 - mn) + fexp2(t1 - mn));
        m[r] = mn;
      }
    }
    __syncthreads();
    p ^= 1;
  }

  #pragma unroll
  for (int r = 0; r < 4; ++r) {
    #pragma unroll
    for (int off = 1; off < 16; off <<= 1) {
      float mo = __shfl_xor(m[r], off);
      float so = __shfl_xor(s[r], off);
      float mn = fmaxf(m[r], mo);
      s[r] = fmaf(s[r], fexp2(m[r] - mn), so * fexp2(mo - mn));
      m[r] = mn;
    }
  }
  if (c == 0) {
    #pragma unroll
    for (int r = 0; r < 4; ++r) {
      size_t idx = (size_t)(half * 4 + z) * VECN + (size_t)batch * NPTS + rowbase + g * 4 + r;
      pm[idx] = m[r];
      ps[idx] = s[r];
    }
  }
}

// Iterations 1..10: fixed per-row normalizer R (1 exp2/entry, pure add-reduce).
__global__ __launch_bounds__(256, 8)
void extrap_fixed(const ushort* __restrict__ xb, const ushort* __restrict__ yb,
                  const float* __restrict__ nhx, const float* __restrict__ nhy,
                  const float* __restrict__ cwarr, const float* __restrict__ Rarr,
                  float* __restrict__ pm, float* __restrict__ ps) {
  EXTRAP_PROLOGUE
  float q[4], Rr[4];
  #pragma unroll
  for (int r = 0; r < 4; ++r) {
    size_t rowi = (size_t)batch * NPTS + rowbase + g * 4 + r;
    Rr[r] = Rarr[(size_t)z * VECN + rowi];
    q[r] = -(nU[rowi] + Rr[r]);
  }

  float s[4] = {0.f, 0.f, 0.f, 0.f};

  EXTRAP_STAGE(0, 0)
  __syncthreads();
  int p = 0;
  for (int ck = 0; ck < NCHUNK; ++ck) {
    if (ck < NCHUNK - 1) EXTRAP_STAGE(p ^ 1, ck + 1)
    #pragma unroll
    for (int t = 0; t < 2; ++t) {
      EXTRAP_MFMA(p, t, acc0, acc1, cw0, cw1)
      #pragma unroll
      for (int r = 0; r < 4; ++r)
        s[r] += fexp2(acc0[r] + q[r]) + fexp2(acc1[r] + q[r]);
    }
    __syncthreads();
    p ^= 1;
  }

  #pragma unroll
  for (int r = 0; r < 4; ++r) {
    #pragma unroll
    for (int off = 1; off < 16; off <<= 1) s[r] += __shfl_xor(s[r], off);
  }
  if (c == 0) {
    #pragma unroll
    for (int r = 0; r < 4; ++r) {
      size_t idx = (size_t)(half * 4 + z) * VECN + (size_t)batch * NPTS + rowbase + g * 4 + r;
      pm[idx] = Rr[r];
      ps[idx] = s[r];
    }
  }
}

// Combine split-K partials, 0.5-averaging, rebuild consumer cw; store per-row lse (R).
__global__ void merge_kernel(const float* __restrict__ pm, const float* __restrict__ ps,
                             float* __restrict__ pot,
                             const float* __restrict__ la2, const float* __restrict__ lb2,
                             const float* __restrict__ nhx, const float* __restrict__ nhy,
                             float* __restrict__ cw, float* __restrict__ Rarr,
                             float* __restrict__ fouts, int avg) {
  int i = blockIdx.x * blockDim.x + threadIdx.x;       // 0 .. 4*VECN
  int z = i >> 14;                                     // VECN = 16384
  int iin = i & (VECN - 1);
  float m0 = pm[i], m1 = pm[(size_t)4 * VECN + i];
  float s0 = ps[i], s1 = ps[(size_t)4 * VECN + i];
  float mn = fmaxf(m0, m1);
  float s  = fmaf(s0, fexp2(m0 - mn), s1 * fexp2(m1 - mn));
  s = fmaxf(s, 1e-38f);                                // guard log2(0)
  float lse = mn + flog2(s);                           // log2-units row LSE
  float val = -LN2 * lse;
  if (avg) {
    val = 0.5f * (val + pot[i]);
    pot[i] = val;
    Rarr[i] = lse;                                     // normalizer for this job's next pass
    int cjob = z ^ (z >> 1);                           // 0,1 self; 2<->3
    bool colx = (cjob == 0 || cjob == 3);              // consumer's column side
    const float* lw2 = colx ? la2 : lb2;
    const float* nh  = colx ? nhx : nhy;
    float wv = fmaf(val, IL2, lw2[iin]);
    cw[(size_t)cjob * VECN + iin] = wv - nh[iin];
  } else {
    fouts[i] = val;
  }
}

// res = ( sum (ge-f)*a + sum (fe-g)*b ) / BATCH  -> single scalar
__global__ void reduce_kernel(const float* __restrict__ fouts,
                              const float* __restrict__ a, const float* __restrict__ b,
                              float* __restrict__ out) {
  const float* f  = fouts;
  const float* g  = fouts + (size_t)VECN;
  const float* ge = fouts + (size_t)2 * VECN;
  const float* fe = fouts + (size_t)3 * VECN;
  int tid = threadIdx.x;
  float acc = 0.f;
  for (int i = tid; i < VECN; i += 1024)
    acc += (ge[i] - f[i]) * a[i] + (fe[i] - g[i]) * b[i];
  #pragma unroll
  for (int off = 32; off; off >>= 1) acc += __shfl_xor(acc, off);
  __shared__ float red[16];
  if ((tid & 63) == 0) red[tid >> 6] = acc;
  __syncthreads();
  if (tid < 64) {
    float v = (tid < 16) ? red[tid] : 0.f;
    #pragma unroll
    for (int off = 8; off; off >>= 1) v += __shfl_xor(v, off);
    if (tid == 0) out[0] = v / (float)BATCH;
  }
}

extern "C" void kernel_launch(void* const* d_in, const int* in_sizes, int n_in,
                              void* d_out, int out_size, void* d_ws, size_t ws_size,
                              hipStream_t stream) {
  const float* x = (const float*)d_in[0];
  const float* a = (const float*)d_in[1];
  const float* y = (const float*)d_in[2];
  const float* b = (const float*)d_in[3];
  char* ws = (char*)d_ws;
  ushort* xb  = (ushort*)(ws + XB_OFF);
  ushort* yb  = (ushort*)(ws + YB_OFF);
  float* nhx  = (float*)(ws + NHX_OFF);
  float* nhy  = (float*)(ws + NHY_OFF);
  float* la2  = (float*)(ws + LA2_OFF);
  float* lb2  = (float*)(ws + LB2_OFF);
  float* pot  = (float*)(ws + POT_OFF);
  float* cw   = (float*)(ws + CW_OFF);
  float* pm   = (float*)(ws + PM_OFF);
  float* ps   = (float*)(ws + PS_OFF);
  float* fouts= (float*)(ws + FOUT_OFF);
  float* Rarr = (float*)(ws + R_OFF);

  prep_convert<<<dim3(2 * VECN / 4), 256, 0, stream>>>(x, y, xb, yb, nhx, nhy);
  prep_vecs<<<dim3(VECN / 256), 256, 0, stream>>>(a, b, nhx, nhy, la2, lb2, pot, cw);

  const dim3 eg((NPTS / 64) * 2, BATCH, 4);
  // iteration 0: online-max (safe, seeds R)
  extrap_online<<<eg, 256, 0, stream>>>(xb, yb, nhx, nhy, cw, pm, ps);
  merge_kernel<<<dim3(4 * VECN / 256), 256, 0, stream>>>(
      pm, ps, pot, la2, lb2, nhx, nhy, cw, Rarr, fouts, 1);
  // iterations 1..9: fixed-R fast path
  for (int it = 1; it < 10; ++it) {
    extrap_fixed<<<eg, 256, 0, stream>>>(xb, yb, nhx, nhy, cw, Rarr, pm, ps);
    merge_kernel<<<dim3(4 * VECN / 256), 256, 0, stream>>>(
        pm, ps, pot, la2, lb2, nhx, nhy, cw, Rarr, fouts, 1);
  }
  // final extrapolation (no averaging) -> f, g, ge, fe
  extrap_fixed<<<eg, 256, 0, stream>>>(xb, yb, nhx, nhy, cw, Rarr, pm, ps);
  merge_kernel<<<dim3(4 * VECN / 256), 256, 0, stream>>>(
      pm, ps, pot, la2, lb2, nhx, nhy, cw, Rarr, fouts, 0);

  reduce_kernel<<<1, 1024, 0, stream>>>(fouts, a, b, (float*)d_out);
}

// Round 11
// 486.343 us; speedup vs baseline: 11.2247x; 10.6533x over previous
//
#include <hip/hip_runtime.h>
#include <stdint.h>

// Problem constants (fixed by setup_inputs): B=8, L=K=2048, D=64
#define BATCH 8
#define NPTS  2048
#define DIM   64
#define VECN  (BATCH*NPTS)   // 16384
#define KH    1024           // split-K half width
#define CHUNK 64             // columns staged per LDS buffer
#define NCHUNK (KH/CHUNK)    // 16

typedef __attribute__((ext_vector_type(8))) short bf16x8;
typedef __attribute__((ext_vector_type(4))) float f32x4;

#define IL2 1.4426950408889634f
#define LN2 0.6931471805599453f

__device__ inline float fexp2(float x) { return __builtin_amdgcn_exp2f(x); }
__device__ inline float flog2(float x) { return __builtin_amdgcn_logf(x); }

// async global->LDS staging (lds dest = uniform base + lane*size; global src per-lane)
__device__ inline void gload_lds16(const void* g, void* l) {
  __builtin_amdgcn_global_load_lds(
      (const __attribute__((address_space(1))) uint32_t*)g,
      (__attribute__((address_space(3))) uint32_t*)l, 16, 0, 0);
}
__device__ inline void gload_lds4(const void* g, void* l) {
  __builtin_amdgcn_global_load_lds(
      (const __attribute__((address_space(1))) uint32_t*)g,
      (__attribute__((address_space(3))) uint32_t*)l, 4, 0, 0);
}

// ---- workspace layout (bytes) ----  (R3-proven layout + Rarr at the end)
static constexpr size_t XB_OFF   = 0;                                   // bf16 x : 2 MB
static constexpr size_t YB_OFF   = (size_t)VECN * DIM * 2;              // bf16 y : 2 MB
static constexpr size_t NX2_OFF  = YB_OFF * 2;                          // ||x||^2 * IL2
static constexpr size_t NY2_OFF  = NX2_OFF + (size_t)VECN * 4;
static constexpr size_t LA2_OFF  = NY2_OFF + (size_t)VECN * 4;          // log2(a)
static constexpr size_t LB2_OFF  = LA2_OFF + (size_t)VECN * 4;          // log2(b)
static constexpr size_t POT_OFF  = LB2_OFF + (size_t)VECN * 4;          // 4 pots
static constexpr size_t NW_OFF   = POT_OFF + (size_t)4 * VECN * 4;      // float2 {norm, pot+lw} per job
static constexpr size_t PM_OFF   = NW_OFF + (size_t)4 * VECN * 8;       // partial max/R [2][4][VECN]
static constexpr size_t PS_OFF   = PM_OFF + (size_t)8 * VECN * 4;       // partial sum [2][4][VECN]
static constexpr size_t FOUT_OFF = PS_OFF + (size_t)8 * VECN * 4;       // f,g,ge,fe
static constexpr size_t R_OFF    = FOUT_OFF + (size_t)4 * VECN * 4;     // per-row lse (log2) [4][VECN]

__device__ inline ushort f2bf(float f) {
  uint32_t u = __float_as_uint(f);
  u += 0x7fffu + ((u >> 16) & 1u);   // RNE
  return (ushort)(u >> 16);
}

// One wave per row: convert to bf16 + exact f32 squared norm (scaled by IL2).
__global__ void prep_convert(const float* __restrict__ x, const float* __restrict__ y,
                             ushort* __restrict__ xb, ushort* __restrict__ yb,
                             float* __restrict__ nx2, float* __restrict__ ny2) {
  int wid  = (blockIdx.x * blockDim.x + threadIdx.x) >> 6;
  int lane = threadIdx.x & 63;
  const float* src; ushort* dst; float* nrm; int row;
  if (wid < VECN) { src = x; dst = xb; nrm = nx2; row = wid; }
  else            { src = y; dst = yb; nrm = ny2; row = wid - VECN; }
  float v = src[(size_t)row * DIM + lane];
  dst[(size_t)row * DIM + lane] = f2bf(v);
  float sq = v * v;
  #pragma unroll
  for (int off = 32; off; off >>= 1) sq += __shfl_xor(sq, off);
  if (lane == 0) nrm[row] = sq * IL2;
}

// log2-weights, zero pots, init nw[z] = {V-side norm, V-side log2 weight}
__global__ void prep_vecs(const float* __restrict__ a, const float* __restrict__ b,
                          const float* __restrict__ nx2, const float* __restrict__ ny2,
                          float* __restrict__ la2, float* __restrict__ lb2,
                          float* __restrict__ pot, float2* __restrict__ nw) {
  int i = blockIdx.x * blockDim.x + threadIdx.x;
  float l2a = log2f(a[i]);
  float l2b = log2f(b[i]);
  la2[i] = l2a;
  lb2[i] = l2b;
  float nxv = nx2[i], nyv = ny2[i];
  nw[i]                     = make_float2(nxv, l2a);  // z0 xx: V=x
  nw[(size_t)VECN + i]      = make_float2(nyv, l2b);  // z1 yy: V=y
  nw[(size_t)2 * VECN + i]  = make_float2(nyv, l2b);  // z2 xy: V=y (uses pyx+lb)
  nw[(size_t)3 * VECN + i]  = make_float2(nxv, l2a);  // z3 yx: V=x (uses pxy+la)
  #pragma unroll
  for (int j = 0; j < 4; ++j) pot[(size_t)j * VECN + i] = 0.f;
}

// Iteration-0 extrap: online-max flash-LSE (exact R3-proven body), seeds R via merge.
// grid: ((NPTS/64)*2, BATCH, 4 jobs); block 256 (4 waves, 16 rows each)
__global__ __launch_bounds__(256, 8)
void extrap_online(const ushort* __restrict__ xb, const ushort* __restrict__ yb,
                   const float* __restrict__ nx2, const float* __restrict__ ny2,
                   const float2* __restrict__ nw,
                   float* __restrict__ pm, float* __restrict__ ps) {
  __shared__ char vlds[2][CHUNK * 128];   // 2 x 8 KB, swizzled content
  __shared__ char nwlds[2][CHUNK * 8];    // 2 x 512 B, linear float2

  const int rb    = blockIdx.x >> 1;
  const int half  = blockIdx.x & 1;
  const int batch = blockIdx.y;
  const int z     = blockIdx.z;
  const ushort *U, *V; const float *nU2;
  switch (z) {
    case 0:  U = xb; V = xb; nU2 = nx2; break; // xx
    case 1:  U = yb; V = yb; nU2 = ny2; break; // yy
    case 2:  U = xb; V = yb; nU2 = nx2; break; // xy
    default: U = yb; V = xb; nU2 = ny2; break; // yx
  }
  const int lane = threadIdx.x & 63;
  const int w    = threadIdx.x >> 6;
  const int g    = lane >> 4;
  const int c    = lane & 15;
  const int rowbase = rb * 64 + w * 16;

  const ushort* Ub  = U + ((size_t)batch * NPTS + rowbase) * DIM;
  const char*   Vch = (const char*)(V + ((size_t)batch * NPTS + half * KH) * DIM); // 128B rows
  const char*   nwch = (const char*)(nw + (size_t)z * VECN + (size_t)batch * NPTS + half * KH);

  bf16x8 a0 = *(const bf16x8*)(Ub + (size_t)c * DIM + g * 8);
  bf16x8 a1 = *(const bf16x8*)(Ub + (size_t)c * DIM + 32 + g * 8);

  float nxr2[4];
  #pragma unroll
  for (int r = 0; r < 4; ++r) nxr2[r] = nU2[(size_t)batch * NPTS + rowbase + g * 4 + r];

  const size_t lane_voff = ((size_t)(lane >> 3)) * 128
                         + (size_t)((((lane & 7) ^ (lane >> 3)) << 4));

  float m[4], s[4];
  #pragma unroll
  for (int r = 0; r < 4; ++r) { m[r] = -INFINITY; s[r] = 0.f; }

  auto stage = [&](int p, int ck) {
    const char* gbase = Vch + (size_t)ck * CHUNK * 128;
    #pragma unroll
    for (int i = 0; i < 2; ++i) {
      int j = w * 2 + i;                                  // 1 KB slab = 8 rows
      gload_lds16(gbase + (size_t)j * 1024 + lane_voff, &vlds[p][j * 1024]);
    }
    if (w == 0) {
      const char* gn = nwch + (size_t)ck * CHUNK * 8;
      gload_lds4(gn + lane * 4,       &nwlds[p][0]);
      gload_lds4(gn + 256 + lane * 4, &nwlds[p][256]);
    }
  };

  auto compute = [&](int p) {
    #pragma unroll
    for (int t = 0; t < 2; ++t) {
      const int rr0 = t * 32 + c;
      const int rr1 = rr0 + 16;
      const int x0 = (rr0 & 7) << 4;           // rr1&7 == rr0&7
      const char* pv0 = &vlds[p][rr0 * 128];
      const char* pv1 = &vlds[p][rr1 * 128];
      bf16x8 b0a = *(const bf16x8*)(pv0 + ((g * 16) ^ x0));
      bf16x8 b0b = *(const bf16x8*)(pv0 + ((64 + g * 16) ^ x0));
      bf16x8 b1a = *(const bf16x8*)(pv1 + ((g * 16) ^ x0));
      bf16x8 b1b = *(const bf16x8*)(pv1 + ((64 + g * 16) ^ x0));
      float2 nw0 = *(const float2*)&nwlds[p][rr0 * 8];
      float2 nw1 = *(const float2*)&nwlds[p][rr1 * 8];

      f32x4 acc0 = {0.f, 0.f, 0.f, 0.f}, acc1 = {0.f, 0.f, 0.f, 0.f};
      acc0 = __builtin_amdgcn_mfma_f32_16x16x32_bf16(a0, b0a, acc0, 0, 0, 0);
      acc0 = __builtin_amdgcn_mfma_f32_16x16x32_bf16(a1, b0b, acc0, 0, 0, 0);
      acc1 = __builtin_amdgcn_mfma_f32_16x16x32_bf16(a0, b1a, acc1, 0, 0, 0);
      acc1 = __builtin_amdgcn_mfma_f32_16x16x32_bf16(a1, b1b, acc1, 0, 0, 0);

      #pragma unroll
      for (int r = 0; r < 4; ++r) {
        float d0 = fmaxf(fmaf(-2.f * IL2, acc0[r], nxr2[r] + nw0.x), 0.f);
        float d1 = fmaxf(fmaf(-2.f * IL2, acc1[r], nxr2[r] + nw1.x), 0.f);
        float t0 = nw0.y - d0;
        float t1 = nw1.y - d1;
        float mn = fmaxf(m[r], fmaxf(t0, t1));       // v_max3
        s[r] = fmaf(s[r], fexp2(m[r] - mn), fexp2(t0 - mn) + fexp2(t1 - mn));
        m[r] = mn;
      }
    }
  };

  stage(0, 0);
  __syncthreads();
  int p = 0;
  for (int ck = 0; ck < NCHUNK; ++ck) {
    if (ck < NCHUNK - 1) stage(p ^ 1, ck + 1);   // prefetch in flight during compute
    compute(p);
    __syncthreads();
    p ^= 1;
  }

  #pragma unroll
  for (int r = 0; r < 4; ++r) {
    #pragma unroll
    for (int off = 1; off < 16; off <<= 1) {
      float mo = __shfl_xor(m[r], off);
      float so = __shfl_xor(s[r], off);
      float mn = fmaxf(m[r], mo);
      s[r] = fmaf(s[r], fexp2(m[r] - mn), so * fexp2(mo - mn));
      m[r] = mn;
    }
  }
  if (c == 0) {
    #pragma unroll
    for (int r = 0; r < 4; ++r) {
      size_t idx = (size_t)(half * 4 + z) * VECN + (size_t)batch * NPTS + rowbase + g * 4 + r;
      pm[idx] = m[r];
      ps[idx] = s[r];
    }
  }
}

// Iterations 1..10: fixed per-row normalizer R (1 exp2/entry, pure add-reduce).
// Same skeleton; inner loop: s += exp2(fmaf(2*IL2, acc, ct + q)).
__global__ __launch_bounds__(256, 8)
void extrap_fixed(const ushort* __restrict__ xb, const ushort* __restrict__ yb,
                  const float* __restrict__ nx2, const float* __restrict__ ny2,
                  const float2* __restrict__ nw, const float* __restrict__ Rarr,
                  float* __restrict__ pm, float* __restrict__ ps) {
  __shared__ char vlds[2][CHUNK * 128];
  __shared__ char nwlds[2][CHUNK * 8];

  const int rb    = blockIdx.x >> 1;
  const int half  = blockIdx.x & 1;
  const int batch = blockIdx.y;
  const int z     = blockIdx.z;
  const ushort *U, *V; const float *nU2;
  switch (z) {
    case 0:  U = xb; V = xb; nU2 = nx2; break; // xx
    case 1:  U = yb; V = yb; nU2 = ny2; break; // yy
    case 2:  U = xb; V = yb; nU2 = nx2; break; // xy
    default: U = yb; V = xb; nU2 = ny2; break; // yx
  }
  const int lane = threadIdx.x & 63;
  const int w    = threadIdx.x >> 6;
  const int g    = lane >> 4;
  const int c    = lane & 15;
  const int rowbase = rb * 64 + w * 16;

  const ushort* Ub  = U + ((size_t)batch * NPTS + rowbase) * DIM;
  const char*   Vch = (const char*)(V + ((size_t)batch * NPTS + half * KH) * DIM);
  const char*   nwch = (const char*)(nw + (size_t)z * VECN + (size_t)batch * NPTS + half * KH);

  bf16x8 a0 = *(const bf16x8*)(Ub + (size_t)c * DIM + g * 8);
  bf16x8 a1 = *(const bf16x8*)(Ub + (size_t)c * DIM + 32 + g * 8);

  float q[4], Rr[4];
  #pragma unroll
  for (int r = 0; r < 4; ++r) {
    size_t rowi = (size_t)batch * NPTS + rowbase + g * 4 + r;
    Rr[r] = Rarr[(size_t)z * VECN + rowi];
    q[r]  = -(nU2[rowi] + Rr[r]);        // -(norm_row + R_row), log2 units
  }

  const size_t lane_voff = ((size_t)(lane >> 3)) * 128
                         + (size_t)((((lane & 7) ^ (lane >> 3)) << 4));

  float s[4] = {0.f, 0.f, 0.f, 0.f};

  auto stage = [&](int p, int ck) {
    const char* gbase = Vch + (size_t)ck * CHUNK * 128;
    #pragma unroll
    for (int i = 0; i < 2; ++i) {
      int j = w * 2 + i;
      gload_lds16(gbase + (size_t)j * 1024 + lane_voff, &vlds[p][j * 1024]);
    }
    if (w == 0) {
      const char* gn = nwch + (size_t)ck * CHUNK * 8;
      gload_lds4(gn + lane * 4,       &nwlds[p][0]);
      gload_lds4(gn + 256 + lane * 4, &nwlds[p][256]);
    }
  };

  auto compute = [&](int p) {
    #pragma unroll
    for (int t = 0; t < 2; ++t) {
      const int rr0 = t * 32 + c;
      const int rr1 = rr0 + 16;
      const int x0 = (rr0 & 7) << 4;
      const char* pv0 = &vlds[p][rr0 * 128];
      const char* pv1 = &vlds[p][rr1 * 128];
      bf16x8 b0a = *(const bf16x8*)(pv0 + ((g * 16) ^ x0));
      bf16x8 b0b = *(const bf16x8*)(pv0 + ((64 + g * 16) ^ x0));
      bf16x8 b1a = *(const bf16x8*)(pv1 + ((g * 16) ^ x0));
      bf16x8 b1b = *(const bf16x8*)(pv1 + ((64 + g * 16) ^ x0));
      float2 nw0 = *(const float2*)&nwlds[p][rr0 * 8];
      float2 nw1 = *(const float2*)&nwlds[p][rr1 * 8];
      float ct0 = nw0.y - nw0.x;         // (pot+lw) - norm_col
      float ct1 = nw1.y - nw1.x;

      f32x4 acc0 = {0.f, 0.f, 0.f, 0.f}, acc1 = {0.f, 0.f, 0.f, 0.f};
      acc0 = __builtin_amdgcn_mfma_f32_16x16x32_bf16(a0, b0a, acc0, 0, 0, 0);
      acc0 = __builtin_amdgcn_mfma_f32_16x16x32_bf16(a1, b0b, acc0, 0, 0, 0);
      acc1 = __builtin_amdgcn_mfma_f32_16x16x32_bf16(a0, b1a, acc1, 0, 0, 0);
      acc1 = __builtin_amdgcn_mfma_f32_16x16x32_bf16(a1, b1b, acc1, 0, 0, 0);

      #pragma unroll
      for (int r = 0; r < 4; ++r) {
        s[r] += fexp2(fmaf(2.f * IL2, acc0[r], ct0 + q[r]));
        s[r] += fexp2(fmaf(2.f * IL2, acc1[r], ct1 + q[r]));
      }
    }
  };

  stage(0, 0);
  __syncthreads();
  int p = 0;
  for (int ck = 0; ck < NCHUNK; ++ck) {
    if (ck < NCHUNK - 1) stage(p ^ 1, ck + 1);
    compute(p);
    __syncthreads();
    p ^= 1;
  }

  #pragma unroll
  for (int r = 0; r < 4; ++r) {
    #pragma unroll
    for (int off = 1; off < 16; off <<= 1) s[r] += __shfl_xor(s[r], off);
  }
  if (c == 0) {
    #pragma unroll
    for (int r = 0; r < 4; ++r) {
      size_t idx = (size_t)(half * 4 + z) * VECN + (size_t)batch * NPTS + rowbase + g * 4 + r;
      pm[idx] = Rr[r];
      ps[idx] = s[r];
    }
  }
}

// Combine split-K partials, 0.5-averaging, update consumer nw.y; store per-row lse (R).
__global__ void merge_kernel(const float* __restrict__ pm, const float* __restrict__ ps,
                             float* __restrict__ pot,
                             const float* __restrict__ la2, const float* __restrict__ lb2,
                             float2* __restrict__ nw, float* __restrict__ Rarr,
                             float* __restrict__ fouts, int avg) {
  int i = blockIdx.x * blockDim.x + threadIdx.x;       // 0 .. 4*VECN
  int z = i >> 14;                                     // VECN = 16384
  int iin = i & (VECN - 1);
  float m0 = pm[i], m1 = pm[(size_t)4 * VECN + i];
  float s0 = ps[i], s1 = ps[(size_t)4 * VECN + i];
  float mn = fmaxf(m0, m1);
  float s  = fmaf(s0, fexp2(m0 - mn), s1 * fexp2(m1 - mn));
  s = fmaxf(s, 1e-38f);                                // guard log2(0)
  float lse = mn + flog2(s);                           // log2-units row LSE
  float val = -LN2 * lse;
  if (avg) {
    val = 0.5f * (val + pot[i]);
    pot[i] = val;
    Rarr[i] = lse;                                     // normalizer for this job's next pass
    int cjob = z ^ (z >> 1);                           // 0,1 self; 2<->3
    const float* lw2 = (z & 1) ? lb2 : la2;
    nw[(size_t)cjob * VECN + iin].y = fmaf(val, IL2, lw2[iin]);
  } else {
    fouts[i] = val;
  }
}

// res = ( sum (ge-f)*a + sum (fe-g)*b ) / BATCH  -> single scalar
__global__ void reduce_kernel(const float* __restrict__ fouts,
                              const float* __restrict__ a, const float* __restrict__ b,
                              float* __restrict__ out) {
  const float* f  = fouts;
  const float* g  = fouts + (size_t)VECN;
  const float* ge = fouts + (size_t)2 * VECN;
  const float* fe = fouts + (size_t)3 * VECN;
  int tid = threadIdx.x;
  float acc = 0.f;
  for (int i = tid; i < VECN; i += 1024)
    acc += (ge[i] - f[i]) * a[i] + (fe[i] - g[i]) * b[i];
  #pragma unroll
  for (int off = 32; off; off >>= 1) acc += __shfl_xor(acc, off);
  __shared__ float red[16];
  if ((tid & 63) == 0) red[tid >> 6] = acc;
  __syncthreads();
  if (tid < 64) {
    float v = (tid < 16) ? red[tid] : 0.f;
    #pragma unroll
    for (int off = 8; off; off >>= 1) v += __shfl_xor(v, off);
    if (tid == 0) out[0] = v / (float)BATCH;
  }
}

extern "C" void kernel_launch(void* const* d_in, const int* in_sizes, int n_in,
                              void* d_out, int out_size, void* d_ws, size_t ws_size,
                              hipStream_t stream) {
  const float* x = (const float*)d_in[0];
  const float* a = (const float*)d_in[1];
  const float* y = (const float*)d_in[2];
  const float* b = (const float*)d_in[3];
  char* ws = (char*)d_ws;
  ushort* xb  = (ushort*)(ws + XB_OFF);
  ushort* yb  = (ushort*)(ws + YB_OFF);
  float* nx2  = (float*)(ws + NX2_OFF);
  float* ny2  = (float*)(ws + NY2_OFF);
  float* la2  = (float*)(ws + LA2_OFF);
  float* lb2  = (float*)(ws + LB2_OFF);
  float* pot  = (float*)(ws + POT_OFF);
  float2* nw  = (float2*)(ws + NW_OFF);
  float* pm   = (float*)(ws + PM_OFF);
  float* ps   = (float*)(ws + PS_OFF);
  float* fouts= (float*)(ws + FOUT_OFF);
  float* Rarr = (float*)(ws + R_OFF);

  prep_convert<<<dim3(2 * VECN / 4), 256, 0, stream>>>(x, y, xb, yb, nx2, ny2);
  prep_vecs<<<dim3(VECN / 256), 256, 0, stream>>>(a, b, nx2, ny2, la2, lb2, pot, nw);

  const dim3 eg((NPTS / 64) * 2, BATCH, 4);
  // iteration 0: online-max (safe, seeds R)
  extrap_online<<<eg, 256, 0, stream>>>(xb, yb, nx2, ny2, nw, pm, ps);
  merge_kernel<<<dim3(4 * VECN / 256), 256, 0, stream>>>(
      pm, ps, pot, la2, lb2, nw, Rarr, fouts, 1);
  // iterations 1..9: fixed-R fast path
  for (int it = 1; it < 10; ++it) {
    extrap_fixed<<<eg, 256, 0, stream>>>(xb, yb, nx2, ny2, nw, Rarr, pm, ps);
    merge_kernel<<<dim3(4 * VECN / 256), 256, 0, stream>>>(
        pm, ps, pot, la2, lb2, nw, Rarr, fouts, 1);
  }
  // final extrapolation (no averaging) -> f, g, ge, fe
  extrap_fixed<<<eg, 256, 0, stream>>>(xb, yb, nx2, ny2, nw, Rarr, pm, ps);
  merge_kernel<<<dim3(4 * VECN / 256), 256, 0, stream>>>(
      pm, ps, pot, la2, lb2, nw, Rarr, fouts, 0);

  reduce_kernel<<<1, 1024, 0, stream>>>(fouts, a, b, (float*)d_out);
}